// Round 14
// baseline (515.245 us; speedup 1.0000x reference)
//
#include <hip/hip_runtime.h>
#include <cstdint>
#include <cstddef>

// ---------------------------------------------------------------------------
// FeedForwardQuantum: out = W2 @ relu(W1 @ (cos(theta)*cos(x[:,:8])) + b1) + b2
// M = 32768, K = 4096 (FFN), N = 1024 (EMBED).
// Round 14: fused GEMM, r13's W1S-drain bug fixed.
//   BUG (r13): vmcnt retires OLDEST-first; W1S DMA was issued newest, so
//   vmcnt(4) left it in flight -> P12 read garbage W1 slice (absmax 4.48).
//   FIX: W1S double-buffered; W1S(u+2) issued at P0 (only VMEM there ->
//   deterministically ordered); counted drains retire exactly one stream:
//   Ledger invariant (P0 entry): 5 outstanding = [W1S(u+1), B(u+1)x4].
//    P0 : a-frag reads; Q00+Q01; issue W1S(u+2)->buf[p];
//         vmcnt(5) [retires W1S(u+1)]; lgkm0; BAR
//    P12: CSTAGE A(u+1)->LA[p^1] using W1S buf[p^1]; Q11; issue B(u+2)x4;
//         vmcnt(5) [retires B(u+1)x4]; lgkm0 [publish A writes]; BAR
//    P3 : Q10; read b-frags(u+1) from LB[p^1]; lgkm0; BAR
//   WAR: W1S buf[p] last read @P12(u-1), rewritten @P0(u) (>=2 BARs);
//   LA[p^1] last read @P0(u-1); LB[p^1] reads @P3 drained before P12(u+2).
//   Also fixed: W1 slice stored SKEWED (row f at slot f+(f>>3)) so the 8
//   per-gw ds_read_b128 hit distinct banks (was 8-way conflict).
// q (cos(theta)*cos(x)) built once per block in LDS f16; h via v_dot2
// (f16 x f16 + f32). No Hsw round-trip, no h_kernel. Fallback: r11 (297us).
// ---------------------------------------------------------------------------

#define M_TOT 32768L
#define N_DIM 1024
#define K_DIM 4096
#define BM 256
#define BN 256
#define BK 64
#define NT_K (K_DIM / BK)   // 64
#define W1SL 1536L          // W1HB per-slice stride (bytes)

typedef __attribute__((ext_vector_type(8))) short short8;     // 8 x bf16
typedef __attribute__((ext_vector_type(4))) float f32x4;
typedef __attribute__((ext_vector_type(8))) _Float16 half8v;  // 8 x f16
typedef __attribute__((ext_vector_type(2))) _Float16 h2;      // 2 x f16

__device__ __forceinline__ uint16_t f2bf(float f) {
  uint32_t u = __builtin_bit_cast(uint32_t, f);
  uint32_t r = (u + 0x7fffu + ((u >> 16) & 1u)) >> 16;   // RNE
  return (uint16_t)r;
}

__device__ __forceinline__ float dot8(half8v q, half8v w, float c) {
  c = __builtin_amdgcn_fdot2((h2){q[0], q[1]}, (h2){w[0], w[1]}, c, false);
  c = __builtin_amdgcn_fdot2((h2){q[2], q[3]}, (h2){w[2], w[3]}, c, false);
  c = __builtin_amdgcn_fdot2((h2){q[4], q[5]}, (h2){w[4], w[5]}, c, false);
  c = __builtin_amdgcn_fdot2((h2){q[6], q[7]}, (h2){w[6], w[7]}, c, false);
  return c;
}

// ---------------------------------------------------------------------------
// Kernel 1: W2 [1024][4096] fp32 -> bf16, swizzled:
//   elem (e,k) at e*4096 + (k & ~63) + (((k>>3)&7) ^ (e&7))*8 + (k&7)
// ---------------------------------------------------------------------------
__global__ __launch_bounds__(256) void prep_w2(const float* __restrict__ W2,
                                               uint16_t* __restrict__ W2sw) {
  long idx = (long)blockIdx.x * 256 + threadIdx.x;
  long e8 = idx * 8;
  int e = (int)(e8 >> 12);
  int k = (int)(e8 & 4095);
  float4 v0 = *(const float4*)(W2 + e8);
  float4 v1 = *(const float4*)(W2 + e8 + 4);
  union { uint16_t u[8]; uint4 v; } pk;
  pk.u[0] = f2bf(v0.x); pk.u[1] = f2bf(v0.y); pk.u[2] = f2bf(v0.z); pk.u[3] = f2bf(v0.w);
  pk.u[4] = f2bf(v1.x); pk.u[5] = f2bf(v1.y); pk.u[6] = f2bf(v1.z); pk.u[7] = f2bf(v1.w);
  int sg = ((k >> 3) & 7) ^ (e & 7);
  uint16_t* dst = W2sw + (long)e * 4096 + (k & ~63) + sg * 8;
  *(uint4*)dst = pk.v;
}

// ---------------------------------------------------------------------------
// Kernel 2: W1 [4096][8] f32 + b1 [4096] f32 -> 64 per-K-tile slices.
// Slice t (stride 1536 B): f16 row f (8 elems, 16 B) at byte (f+(f>>3))*16
// (skew kills LDS bank conflicts); b1 f32 at 1152 + f*4.
// ---------------------------------------------------------------------------
__global__ __launch_bounds__(256) void prep_w1hb(const float* __restrict__ W1,
                                                 const float* __restrict__ b1,
                                                 char* __restrict__ W1HB) {
  int t = blockIdx.x;            // 0..63
  int tid = threadIdx.x;         // 0..255
  int f = tid >> 2;              // 0..63
  int pr = tid & 3;              // f16-pair 0..3
  const float* src = W1 + ((long)t * 64 + f) * 8 + pr * 2;
  h2 v = {(_Float16)src[0], (_Float16)src[1]};
  *(h2*)(W1HB + (long)t * W1SL + (f + (f >> 3)) * 16 + pr * 4) = v;
  if (tid < 64) {
    *(float*)(W1HB + (long)t * W1SL + 1152 + tid * 4) = b1[t * 64 + tid];
  }
}

// ---------------------------------------------------------------------------
// Kernel 3: fused 256x256 GEMM. 8 waves (2M x 4N), wave tile 128x64,
// acc[8][4] f32x4. LDS: LA+LB dbuf 128K + qsh 4K + W1S[2] 4K = 136 KiB
// (1 block/CU; 512 blocks = 2 rounds).
// ---------------------------------------------------------------------------
__global__ __launch_bounds__(512, 2) void gemm_kernel(const float* __restrict__ x,
                                                      const float* __restrict__ theta,
                                                      const uint16_t* __restrict__ W2sw,
                                                      const char* __restrict__ W1HB,
                                                      const float* __restrict__ b2,
                                                      float* __restrict__ out) {
  __shared__ uint16_t LA[2 * BM * BK];              // 64 KiB
  __shared__ uint16_t LB[2 * BN * BK];              // 64 KiB
  __shared__ __align__(16) _Float16 qsh[256][8];    // 4 KiB
  __shared__ __align__(16) char W1S[2][2048];       // 4 KiB (double-buffered)

  int nwg = gridDim.x;                              // 512 (%8==0)
  int bid = blockIdx.x;
  int cpx = nwg >> 3;
  int sw = (bid & 7) * cpx + (bid >> 3);            // XCD swizzle (bijective)
  const int NTN = N_DIM / BN;                       // 4
  int mt = sw / NTN;
  int nt = sw - mt * NTN;
  long m0 = (long)mt * BM;
  int n0 = nt * BN;

  int tid = threadIdx.x;
  int lane = tid & 63;
  int wave_m = (tid >> 6) >> 2;
  int wave_n = (tid >> 6) & 3;
  int wmB = wave_m * 128;
  int wnB = wave_n * 64;

  int r  = lane & 15;
  int kq = lane >> 4;
  int xr = r & 7;

  int rowS = tid >> 3;        // 0..63
  int gw   = tid & 7;         // granule
  const uint16_t* srcB = W2sw + ((long)(n0 + rowS)) * K_DIM + gw * 8;
  int ldsWB = (tid & ~63) * 8;

#define STAGE_B(p, h, j, t) \
  __builtin_amdgcn_global_load_lds( \
      (const __attribute__((address_space(1))) void*)(srcB + (long)((h)*128 + (j)*64) * K_DIM + (t)*BK), \
      (__attribute__((address_space(3))) void*)&LB[(p)*16384 + ((h)*128 + (j)*64)*BK + ldsWB], 16, 0, 0)

#define STAGE_W1(tcl, bi) \
  __builtin_amdgcn_global_load_lds( \
      (const __attribute__((address_space(1))) void*)(W1HB + (long)(tcl)*W1SL + tid*4), \
      (__attribute__((address_space(3))) void*)&W1S[bi][(tid & ~63)*4], 4, 0, 0)

#define BAR() do { asm volatile("" ::: "memory"); __builtin_amdgcn_s_barrier(); \
                   asm volatile("" ::: "memory"); } while (0)
#define SGB(m_, n_) __builtin_amdgcn_sched_group_barrier((m_), (n_), 0)
#define SB0() __builtin_amdgcn_sched_barrier(0)
#define LGKM0() asm volatile("s_waitcnt lgkmcnt(0)" ::: "memory")
#define VMC(n_) asm volatile("s_waitcnt vmcnt(" #n_ ")" ::: "memory")

#define LDA_F(p, mf_, ks_) \
  (*(const short8*)&LA[(p)*16384 + (wmB + (mf_)*16 + r)*BK + ((((ks_)*4 + kq) ^ xr)*8)])
#define LDB_F(p, nf_, ks_) \
  (*(const short8*)&LB[(p)*16384 + (wnB + (nf_)*16 + r)*BK + ((((ks_)*4 + kq) ^ xr)*8)])

#define MFMA_Q(AARR, BARR, mh, nh) do { \
    _Pragma("unroll") for (int i_ = 0; i_ < 4; ++i_) \
    _Pragma("unroll") for (int j_ = 0; j_ < 2; ++j_) \
    _Pragma("unroll") for (int ks_ = 0; ks_ < 2; ++ks_) \
      acc[(mh)*4 + i_][(nh)*2 + j_] = __builtin_amdgcn_mfma_f32_16x16x32_bf16( \
          AARR[i_][ks_], BARR[j_][ks_], acc[(mh)*4 + i_][(nh)*2 + j_], 0, 0, 0); \
  } while (0)

#define READ_A0(p) do { \
    _Pragma("unroll") for (int i_ = 0; i_ < 4; ++i_) \
    _Pragma("unroll") for (int ks_ = 0; ks_ < 2; ++ks_) \
      a0[i_][ks_] = LDA_F(p, i_, ks_); \
  } while (0)
#define READ_A1(p) do { \
    _Pragma("unroll") for (int i_ = 0; i_ < 4; ++i_) \
    _Pragma("unroll") for (int ks_ = 0; ks_ < 2; ++ks_) \
      a1[i_][ks_] = LDA_F(p, 4 + i_, ks_); \
  } while (0)
#define READ_B0(pn) do { \
    _Pragma("unroll") for (int j_ = 0; j_ < 2; ++j_) \
    _Pragma("unroll") for (int ks_ = 0; ks_ < 2; ++ks_) \
      b0[j_][ks_] = LDB_F(pn, j_, ks_); \
  } while (0)
#define READ_B1V(pn) do { \
    _Pragma("unroll") for (int j_ = 0; j_ < 2; ++j_) \
    _Pragma("unroll") for (int ks_ = 0; ks_ < 2; ++ks_) \
      b1v[j_][ks_] = LDB_F(pn, 2 + j_, ks_); \
  } while (0)

// Compute one 64-row A-region into LA[pdst] from W1S[bufr] (skewed rows):
// h = relu(b1 + q.W1), bf16, XOR-swizzled granule.
#define CSTAGE_A(pdst, bufr_, h, j) do { \
    int row_l = (h)*128 + (j)*64 + rowS; \
    half8v qv = *(const half8v*)&qsh[row_l][0]; \
    const _Float16* W1f_ = (const _Float16*)W1S[bufr_]; \
    union { uint16_t u[8]; uint4 v; } pk_; \
    _Pragma("unroll") for (int jj = 0; jj < 8; ++jj) { \
      half8v wv = *(const half8v*)&W1f_[(gw * 9 + jj) * 8]; \
      float hs = dot8(qv, wv, bb1[jj]); \
      pk_.u[jj] = f2bf(fmaxf(hs, 0.0f)); \
    } \
    *(uint4*)&LA[(pdst)*16384 + row_l*BK + ((gw ^ (row_l & 7))*8)] = pk_.v; \
  } while (0)

#define CSTAGE_ALL(pdst, bufr_) do { \
    const float* b1sf_ = (const float*)(W1S[bufr_] + 1152); \
    float4 bA_ = *(const float4*)&b1sf_[gw * 8]; \
    float4 bB_ = *(const float4*)&b1sf_[gw * 8 + 4]; \
    float bb1[8] = {bA_.x, bA_.y, bA_.z, bA_.w, bB_.x, bB_.y, bB_.z, bB_.w}; \
    CSTAGE_A(pdst, bufr_, 0, 0); CSTAGE_A(pdst, bufr_, 1, 0); \
    CSTAGE_A(pdst, bufr_, 0, 1); CSTAGE_A(pdst, bufr_, 1, 1); \
  } while (0)

  f32x4 acc[8][4];
#pragma unroll
  for (int i = 0; i < 8; ++i)
#pragma unroll
    for (int j = 0; j < 4; ++j) acc[i][j] = (f32x4){0.f, 0.f, 0.f, 0.f};

  short8 a0[4][2];
  short8 a1[4][2];
  short8 b0[2][2];
  short8 b1v[2][2];

  // ---- prologue: build q (f16) in LDS
  {
    int t2 = tid >> 1, hf = tid & 1;
    float4 xv = *(const float4*)(x + (m0 + t2) * 1024 + hf * 4);
    float4 th = *(const float4*)(theta + hf * 4);
    union { _Float16 h[4]; short4 s; } qp;
    qp.h[0] = (_Float16)(__cosf(th.x) * cosf(xv.x));
    qp.h[1] = (_Float16)(__cosf(th.y) * cosf(xv.y));
    qp.h[2] = (_Float16)(__cosf(th.z) * cosf(xv.z));
    qp.h[3] = (_Float16)(__cosf(th.w) * cosf(xv.w));
    *(short4*)&qsh[t2][hf * 4] = qp.s;
  }
  __syncthreads();

  // ---- prologue DMAs, ORDER PINNED (oldest-first ledger):
  //      W1S(0), B(0)x4, W1S(1), B(1)x4   -> 10 outstanding
  STAGE_W1(0, 0);
  SB0();
  STAGE_B(0, 0, 0, 0); STAGE_B(0, 0, 1, 0); STAGE_B(0, 1, 0, 0); STAGE_B(0, 1, 1, 0);
  SB0();
  STAGE_W1(1, 1);
  SB0();
  STAGE_B(1, 0, 0, 1); STAGE_B(1, 0, 1, 1); STAGE_B(1, 1, 0, 1); STAGE_B(1, 1, 1, 1);
  VMC(9);                          // retires W1S(0) exactly
  BAR();                           // publish W1S(0)
  CSTAGE_ALL(0, 0);                // A(0) -> LA[0]
  LGKM0();                         // publish A(0) ds_writes
  VMC(5);                          // retires B(0)x4; leaves [W1S(1), B(1)x4]
  BAR();                           // publish LB buf0 + A(0)
  READ_B0(0);
  READ_B1V(0);

#pragma unroll 2
  for (int u = 0; u < NT_K; ++u) {
    int p = u & 1;
    int tc = (u + 2 < NT_K) ? (u + 2) : (NT_K - 1);   // clamped slice/tile

    // ---- P0: a-frag reads; Q00+Q01; issue W1S(u+2) (only VMEM here)
    READ_A0(p);
    MFMA_Q(a0, b0, 0, 0);
    MFMA_Q(a0, b1v, 0, 1);
    READ_A1(p);
    STAGE_W1(tc, p);                 // dest buf parity = (u+2)&1 = p
    SGB(0x100, 8);                   // a0 reads first
    SGB(0x10, 1);                    // W1S DMA early
#pragma unroll
    for (int s_ = 0; s_ < 8; ++s_) { SGB(0x8, 4); SGB(0x100, 1); }
    VMC(5);                          // retires W1S(u+1) exactly
    LGKM0();
    BAR();

    // ---- P12: compute A(u+1) -> LA[p^1] from W1S[p^1]; Q11; issue B(u+2)x4
    CSTAGE_ALL(p ^ 1, p ^ 1);
    MFMA_Q(a1, b1v, 1, 1);
    STAGE_B(p, 0, 0, tc); STAGE_B(p, 0, 1, tc);
    STAGE_B(p, 1, 0, tc); STAGE_B(p, 1, 1, tc);
    SGB(0x10, 4);                    // B DMAs early
#pragma unroll
    for (int s_ = 0; s_ < 16; ++s_) { SGB(0x100, 2); SGB(0x2, 12); SGB(0x8, 1); }
    SGB(0x200, 4);
    VMC(5);                          // retires B(u+1)x4 exactly
    LGKM0();                         // publish A(u+1) ds_writes
    BAR();

    // ---- P3: Q10; read b-frags of tile u+1 from LB[p^1]
    MFMA_Q(a1, b0, 1, 0);
    READ_B0(p ^ 1);
    READ_B1V(p ^ 1);
#pragma unroll
    for (int s_ = 0; s_ < 6; ++s_) { SGB(0x8, 2); SGB(0x100, 2); }
    SGB(0x8, 4);
    LGKM0();
    BAR();
  }
  VMC(0);                            // drain leftover clamped DMAs

  // ---- epilogue: C/D layout col = lane&15 (n), row = kq*4 + reg (m)
  float bb[4];
#pragma unroll
  for (int nf = 0; nf < 4; ++nf) bb[nf] = b2[n0 + wnB + nf * 16 + r];
  long mbase = m0 + wmB + kq * 4;
#pragma unroll
  for (int mf = 0; mf < 8; ++mf) {
#pragma unroll
    for (int nf = 0; nf < 4; ++nf) {
      int n = n0 + wnB + nf * 16 + r;
#pragma unroll
      for (int rg = 0; rg < 4; ++rg) {
        out[(mbase + mf * 16 + rg) * N_DIM + n] = acc[mf][nf][rg] + bb[nf];
      }
    }
  }
#undef STAGE_B
#undef STAGE_W1
#undef BAR
#undef SGB
#undef SB0
#undef LGKM0
#undef VMC
#undef LDA_F
#undef LDB_F
#undef MFMA_Q
#undef READ_A0
#undef READ_A1
#undef READ_B0
#undef READ_B1V
#undef CSTAGE_A
#undef CSTAGE_ALL
}

// ---------------------------------------------------------------------------
extern "C" void kernel_launch(void* const* d_in, const int* in_sizes, int n_in,
                              void* d_out, int out_size, void* d_ws, size_t ws_size,
                              hipStream_t stream) {
  const float* x     = (const float*)d_in[0];
  const float* theta = (const float*)d_in[1];
  const float* W1    = (const float*)d_in[2];
  const float* b1    = (const float*)d_in[3];
  const float* W2    = (const float*)d_in[4];
  const float* b2    = (const float*)d_in[5];
  float* out = (float*)d_out;

  const size_t W2SW_BYTES = (size_t)N_DIM * K_DIM * 2;   // 8 MiB
  uint16_t* W2sw = (uint16_t*)d_ws;
  char* W1HB = (char*)d_ws + W2SW_BYTES;                 // 64*1536 + 2048 pad

  prep_w2<<<2048, 256, 0, stream>>>(W2, W2sw);
  prep_w1hb<<<64, 256, 0, stream>>>(W1, b1, W1HB);

  unsigned ngb = (unsigned)((M_TOT / BM) * (N_DIM / BN));   // 512
  gemm_kernel<<<ngb, 512, 0, stream>>>(x, theta, W2sw, W1HB, b2, out);
}

// Round 15
// 295.845 us; speedup vs baseline: 1.7416x; 1.7416x over previous
//
#include <hip/hip_runtime.h>
#include <cstdint>
#include <cstddef>

// ---------------------------------------------------------------------------
// FeedForwardQuantum: out = W2 @ relu(W1 @ (cos(theta)*cos(x[:,:8])) + b1) + b2
// M = 32768, K = 4096 (FFN), N = 1024 (EMBED).
// Round 15: REVERT to round-11 (best measured: 297.0us total; GEMM 103us @
// 58.3% MfmaUtil, 0 bank conflicts). Fusion experiments (r13/r14) are
// falsified: fused H adds ~320 LDS ops/CU/tile (36 ds_read_b128/thread) and
// 4x redundant H compute -> 274us/round (2.7x slower), both pipes idle.
// r11 = r5 rotated schedule + T19 SGB MFMA<->ds_read interleave:
//  P0: MFMA(0,0)[a0,b0] interleaved w/ reads {b1v, a1}          ; BAR
//  P1: stage A-j0; MFMA(0,1)[a0,b1v]                            ; BAR
//  P2: stage B-all; MFMA(1,1)[a1,b1v]; vmcnt(6)                 ; BAR
//  P3: MFMA(1,0)[a1,b0] interleaved w/ reads a0(p^1); then
//      reads b0(p^1) (after consumers); stage A-j1              ; BAR
// Stages target tile u+2 (clamped) in the same buffer; vmcnt(6)@P2 drains
// exactly tile u+1's 8 DMAs. Sources pre-swizzled (granule ^= row&7) so
// linear global_load_lds + XOR'd ds_read_b128 is conflict-free.
// Register wall: 8 waves x (128 VGPR + 128 acc) = full 2048/CU.
// ---------------------------------------------------------------------------

#define M_TOT 32768L
#define N_DIM 1024
#define K_DIM 4096
#define BM 256
#define BN 256
#define BK 64
#define NT_K (K_DIM / BK)   // 64
#define CM_MAX 16384L

typedef __attribute__((ext_vector_type(8))) short short8;   // 8 x bf16
typedef __attribute__((ext_vector_type(4))) float f32x4;

__device__ __forceinline__ uint16_t f2bf(float f) {
  uint32_t u = __builtin_bit_cast(uint32_t, f);
  uint32_t r = (u + 0x7fffu + ((u >> 16) & 1u)) >> 16;   // RNE
  return (uint16_t)r;
}

__device__ __forceinline__ void gload_lds16(const void* gsrc, void* ldst) {
  __builtin_amdgcn_global_load_lds(
      (const __attribute__((address_space(1))) void*)gsrc,
      (__attribute__((address_space(3))) void*)ldst, 16, 0, 0);
}

// ---------------------------------------------------------------------------
// Kernel 1: W2 [1024][4096] fp32 -> bf16, swizzled:
//   elem (e,k) at e*4096 + (k & ~63) + (((k>>3)&7) ^ (e&7))*8 + (k&7)
// ---------------------------------------------------------------------------
__global__ __launch_bounds__(256) void prep_w2(const float* __restrict__ W2,
                                               uint16_t* __restrict__ W2sw) {
  long idx = (long)blockIdx.x * 256 + threadIdx.x;
  long e8 = idx * 8;
  int e = (int)(e8 >> 12);
  int k = (int)(e8 & 4095);
  float4 v0 = *(const float4*)(W2 + e8);
  float4 v1 = *(const float4*)(W2 + e8 + 4);
  union { uint16_t u[8]; uint4 v; } pk;
  pk.u[0] = f2bf(v0.x); pk.u[1] = f2bf(v0.y); pk.u[2] = f2bf(v0.z); pk.u[3] = f2bf(v0.w);
  pk.u[4] = f2bf(v1.x); pk.u[5] = f2bf(v1.y); pk.u[6] = f2bf(v1.z); pk.u[7] = f2bf(v1.w);
  int sg = ((k >> 3) & 7) ^ (e & 7);
  uint16_t* dst = W2sw + (long)e * 4096 + (k & ~63) + sg * 8;
  *(uint4*)dst = pk.v;
}

// ---------------------------------------------------------------------------
// Kernel 2 (v3): H[m][f] = relu(sum_i q[m][i]*W1[f][i] + b1[f]), bf16,
// swizzled. 32 rows/block -> 1024 blocks/chunk (16 waves/CU) for store MLP.
// ---------------------------------------------------------------------------
__global__ __launch_bounds__(256) void h_kernel(const float* __restrict__ x,
                                                const float* __restrict__ theta,
                                                const float* __restrict__ W1,
                                                const float* __restrict__ b1,
                                                uint16_t* __restrict__ Hsw) {
  __shared__ float qs[32][8];
  int tid = threadIdx.x;
  long m0 = (long)blockIdx.x * 32;
  int g = blockIdx.y * 256 + tid;       // granule 0..511
  int f0 = g * 8;

  {
    int t = tid >> 3, i = tid & 7;      // 256 threads -> 32 rows x 8
    qs[t][i] = __cosf(theta[i]) * cosf(x[(m0 + t) * 1024 + i]);
  }
  __syncthreads();

  float4 w[16];
#pragma unroll
  for (int j = 0; j < 8; ++j) {
    w[2 * j]     = *(const float4*)(W1 + (long)(f0 + j) * 8);
    w[2 * j + 1] = *(const float4*)(W1 + (long)(f0 + j) * 8 + 4);
  }
  float bb[8];
#pragma unroll
  for (int j = 0; j < 8; ++j) bb[j] = b1[f0 + j];

  int blk = (g >> 3) * 64;
  int gw = g & 7;

#pragma unroll 4
  for (int t = 0; t < 32; ++t) {
    long m = m0 + t;
    float q0 = qs[t][0], q1 = qs[t][1], q2 = qs[t][2], q3 = qs[t][3];
    float q4 = qs[t][4], q5 = qs[t][5], q6 = qs[t][6], q7 = qs[t][7];
    union { uint16_t u[8]; uint4 v; } pk;
#pragma unroll
    for (int j = 0; j < 8; ++j) {
      float h = bb[j];
      h += q0 * w[2 * j].x + q1 * w[2 * j].y + q2 * w[2 * j].z + q3 * w[2 * j].w;
      h += q4 * w[2 * j + 1].x + q5 * w[2 * j + 1].y + q6 * w[2 * j + 1].z + q7 * w[2 * j + 1].w;
      h = fmaxf(h, 0.0f);
      pk.u[j] = f2bf(h);
    }
    int sg = gw ^ ((int)m & 7);
    *(uint4*)&Hsw[m * K_DIM + blk + sg * 8] = pk.v;
  }
}

// ---------------------------------------------------------------------------
// Kernel 3: 256x256 GEMM — round-9/11 configuration (verbatim).
// 8 waves (2M x 4N), wave tile 128x64, acc[8][4] f32x4.
// LDS: A,B double-buffered [2][256][64] bf16 = 128 KiB.
// ---------------------------------------------------------------------------
__global__ __launch_bounds__(512, 2) void gemm_kernel(const uint16_t* __restrict__ Hsw,
                                                      const uint16_t* __restrict__ W2sw,
                                                      const float* __restrict__ b2,
                                                      float* __restrict__ out) {
  __shared__ uint16_t LA[2 * BM * BK];   // 64 KiB
  __shared__ uint16_t LB[2 * BN * BK];   // 64 KiB

  int nwg = gridDim.x;
  int bid = blockIdx.x;
  int sw = bid;
  if ((nwg & 7) == 0) { int cpx = nwg >> 3; sw = (bid & 7) * cpx + (bid >> 3); }
  const int NTN = N_DIM / BN;            // 4
  int mt = sw / NTN;
  int nt = sw - mt * NTN;
  long m0 = (long)mt * BM;
  int n0 = nt * BN;

  int tid = threadIdx.x;
  int lane = tid & 63;
  int wave_m = (tid >> 6) >> 2;          // 0..1
  int wave_n = (tid >> 6) & 3;           // 0..3
  int wmB = wave_m * 128;
  int wnB = wave_n * 64;

  int r  = lane & 15;
  int kq = lane >> 4;
  int xr = r & 7;

  int rowS = tid >> 3;
  int colS = (tid & 7) * 8;
  const uint16_t* srcA = Hsw  + (m0 + rowS) * K_DIM + colS;
  const uint16_t* srcB = W2sw + ((long)(n0 + rowS)) * K_DIM + colS;
  int ldsWB = (tid & ~63) * 8;

#define STAGE_A(p, h, j, t) \
  gload_lds16(srcA + (long)((h)*128 + (j)*64) * K_DIM + (t)*BK, \
              &LA[(p)*16384 + ((h)*128 + (j)*64)*BK + ldsWB])
#define STAGE_B(p, h, j, t) \
  gload_lds16(srcB + (long)((h)*128 + (j)*64) * K_DIM + (t)*BK, \
              &LB[(p)*16384 + ((h)*128 + (j)*64)*BK + ldsWB])

#define BAR() do { asm volatile("" ::: "memory"); __builtin_amdgcn_s_barrier(); \
                   asm volatile("" ::: "memory"); } while (0)
#define SGB(m_, n_) __builtin_amdgcn_sched_group_barrier((m_), (n_), 0)

#define LDA_F(p, mf_, ks_) \
  (*(const short8*)&LA[(p)*16384 + (wmB + (mf_)*16 + r)*BK + ((((ks_)*4 + kq) ^ xr)*8)])
#define LDB_F(p, nf_, ks_) \
  (*(const short8*)&LB[(p)*16384 + (wnB + (nf_)*16 + r)*BK + ((((ks_)*4 + kq) ^ xr)*8)])

#define MFMA_Q(AARR, BARR, mh, nh) do { \
    _Pragma("unroll") for (int i_ = 0; i_ < 4; ++i_) \
    _Pragma("unroll") for (int j_ = 0; j_ < 2; ++j_) \
    _Pragma("unroll") for (int ks_ = 0; ks_ < 2; ++ks_) \
      acc[(mh)*4 + i_][(nh)*2 + j_] = __builtin_amdgcn_mfma_f32_16x16x32_bf16( \
          AARR[i_][ks_], BARR[j_][ks_], acc[(mh)*4 + i_][(nh)*2 + j_], 0, 0, 0); \
  } while (0)

#define READ_B1V(p) do { \
    _Pragma("unroll") for (int j_ = 0; j_ < 2; ++j_) \
    _Pragma("unroll") for (int ks_ = 0; ks_ < 2; ++ks_) \
      b1v[j_][ks_] = LDB_F(p, 2 + j_, ks_); \
  } while (0)
#define READ_A1(p) do { \
    _Pragma("unroll") for (int i_ = 0; i_ < 4; ++i_) \
    _Pragma("unroll") for (int ks_ = 0; ks_ < 2; ++ks_) \
      a1[i_][ks_] = LDA_F(p, 4 + i_, ks_); \
  } while (0)
#define READ_A0(pn) do { \
    _Pragma("unroll") for (int i_ = 0; i_ < 4; ++i_) \
    _Pragma("unroll") for (int ks_ = 0; ks_ < 2; ++ks_) \
      a0[i_][ks_] = LDA_F(pn, i_, ks_); \
  } while (0)
#define READ_B0(pn) do { \
    _Pragma("unroll") for (int j_ = 0; j_ < 2; ++j_) \
    _Pragma("unroll") for (int ks_ = 0; ks_ < 2; ++ks_) \
      b0[j_][ks_] = LDB_F(pn, j_, ks_); \
  } while (0)

  f32x4 acc[8][4];
#pragma unroll
  for (int i = 0; i < 8; ++i)
#pragma unroll
    for (int j = 0; j < 4; ++j) acc[i][j] = (f32x4){0.f, 0.f, 0.f, 0.f};

  short8 a0[4][2];   // mh0 frags (read @P3 of prev tile; dead after P1)
  short8 a1[4][2];   // mh1 frags (read @P0)
  short8 b0[2][2];   // nh0 frags (read late-P3 prev; consumed P0 + P3)
  short8 b1v[2][2];  // nh1 frags (read @P0; consumed P1/P2)

  // ---- prologue: tile0 -> buf0, tile1 -> buf1 (8 DMAs each)
#pragma unroll
  for (int h = 0; h < 2; ++h)
#pragma unroll
    for (int j = 0; j < 2; ++j) STAGE_A(0, h, j, 0);
#pragma unroll
  for (int h = 0; h < 2; ++h)
#pragma unroll
    for (int j = 0; j < 2; ++j) STAGE_B(0, h, j, 0);
#pragma unroll
  for (int h = 0; h < 2; ++h)
#pragma unroll
    for (int j = 0; j < 2; ++j) STAGE_A(1, h, j, 1);
#pragma unroll
  for (int h = 0; h < 2; ++h)
#pragma unroll
    for (int j = 0; j < 2; ++j) STAGE_B(1, h, j, 1);
  asm volatile("s_waitcnt vmcnt(8)" ::: "memory");   // own tile-0 DMAs landed
  BAR();                                             // block-wide landed
  READ_A0(0);
  READ_B0(0);

#pragma unroll 2
  for (int u = 0; u < NT_K; ++u) {
    int p = u & 1;
    int tc = (u + 2 < NT_K) ? (u + 2) : (NT_K - 1);   // clamped stage tile

    // ---- P0: MFMA(0,0) interleaved with reads {b1v, a1}
    MFMA_Q(a0, b0, 0, 0);
    READ_B1V(p);
    READ_A1(p);
#pragma unroll
    for (int s_ = 0; s_ < 12; ++s_) { SGB(0x8, 1); SGB(0x100, 1); }
    SGB(0x8, 4);
    BAR();

    // ---- P1: stage A-j0 of tc (issue first); MFMA(0,1)
    STAGE_A(p, 0, 0, tc); STAGE_A(p, 1, 0, tc);
    MFMA_Q(a0, b1v, 0, 1);
    SGB(0x10, 1); SGB(0x8, 8); SGB(0x10, 1); SGB(0x8, 8);
    BAR();

    // ---- P2: stage all B of tc; MFMA(1,1); counted vmcnt before BAR
    STAGE_B(p, 0, 0, tc); STAGE_B(p, 0, 1, tc);
    STAGE_B(p, 1, 0, tc); STAGE_B(p, 1, 1, tc);
    MFMA_Q(a1, b1v, 1, 1);
#pragma unroll
    for (int s_ = 0; s_ < 4; ++s_) { SGB(0x10, 1); SGB(0x8, 4); }
    asm volatile("s_waitcnt vmcnt(6)" ::: "memory");
    BAR();

    // ---- P3: MFMA(1,0) interleaved with a0 reads (p^1); b0 reads last
    //          (WAR: after their consuming MFMAs); stage A-j1 of tc
    READ_A0(p ^ 1);
    MFMA_Q(a1, b0, 1, 0);
    READ_B0(p ^ 1);
    STAGE_A(p, 0, 1, tc); STAGE_A(p, 1, 1, tc);
#pragma unroll
    for (int s_ = 0; s_ < 8; ++s_) { SGB(0x8, 1); SGB(0x100, 1); }
    SGB(0x10, 2); SGB(0x8, 8); SGB(0x100, 4);
    BAR();
  }

  // ---- epilogue: C/D layout col = lane&15 (n), row = kq*4 + reg (m)
  float bb[4];
#pragma unroll
  for (int nf = 0; nf < 4; ++nf) bb[nf] = b2[n0 + wnB + nf * 16 + r];
  long mbase = m0 + wmB + kq * 4;
#pragma unroll
  for (int mf = 0; mf < 8; ++mf) {
#pragma unroll
    for (int nf = 0; nf < 4; ++nf) {
      int n = n0 + wnB + nf * 16 + r;
#pragma unroll
      for (int rg = 0; rg < 4; ++rg) {
        out[(mbase + mf * 16 + rg) * N_DIM + n] = acc[mf][nf][rg] + bb[nf];
      }
    }
  }
#undef STAGE_A
#undef STAGE_B
#undef BAR
#undef SGB
#undef LDA_F
#undef LDB_F
#undef MFMA_Q
#undef READ_B1V
#undef READ_A1
#undef READ_A0
#undef READ_B0
}

// ---------------------------------------------------------------------------
extern "C" void kernel_launch(void* const* d_in, const int* in_sizes, int n_in,
                              void* d_out, int out_size, void* d_ws, size_t ws_size,
                              hipStream_t stream) {
  const float* x     = (const float*)d_in[0];
  const float* theta = (const float*)d_in[1];
  const float* W1    = (const float*)d_in[2];
  const float* b1    = (const float*)d_in[3];
  const float* W2    = (const float*)d_in[4];
  const float* b2    = (const float*)d_in[5];
  float* out = (float*)d_out;

  const size_t W2SW_BYTES = (size_t)N_DIM * K_DIM * 2;   // 8 MiB
  uint16_t* W2sw = (uint16_t*)d_ws;
  uint16_t* Hsw  = (uint16_t*)((char*)d_ws + W2SW_BYTES);

  size_t avail = ws_size > W2SW_BYTES ? ws_size - W2SW_BYTES : 0;
  long CM = (long)(avail / ((size_t)K_DIM * 2));
  CM &= ~255L;                       // multiple of BM=256
  if (CM > CM_MAX) CM = CM_MAX;      // keep H-chunk (134 MB) L3-resident
  if (CM < 256) CM = 256;

  prep_w2<<<2048, 256, 0, stream>>>(W2, W2sw);

  for (long m0 = 0; m0 < M_TOT; m0 += CM) {
    long mc = M_TOT - m0;
    if (mc > CM) mc = CM;
    dim3 gA((unsigned)(mc / 32), 2);
    h_kernel<<<gA, 256, 0, stream>>>(x + m0 * N_DIM, theta, W1, b1, Hsw);
    unsigned ngb = (unsigned)((mc / BM) * (N_DIM / BN));
    gemm_kernel<<<ngb, 512, 0, stream>>>(Hsw, W2sw, b2, out + m0 * N_DIM);
  }
}